// Round 9
// baseline (371.145 us; speedup 1.0000x reference)
//
#include <hip/hip_runtime.h>
#include <hip/hip_bf16.h>

// ---------------- problem constants ----------------
#define N_NODES 10000
#define E_REAL  80000
#define E_TOTAL 90000
#define IN_DIM  768
#define HID     512
#define HEADS   4
#define OUT_DIM 768
#define HD1     (HEADS * HID)   // 2048
#define NEG_SLOPE 0.2f
#define H1_HSTRIDE (N_NODES * HID)   // 5,120,000 elements per head slice

typedef unsigned short ushort_t;
typedef unsigned int uint_t;

// ---------------- bf16 helpers ----------------
__device__ inline float b2f(ushort_t u) { return __uint_as_float(((uint_t)u) << 16); }
__device__ inline ushort_t f2b(float f) {
    __hip_bfloat16 h = __float2bfloat16(f);   // RNE
    return *reinterpret_cast<ushort_t*>(&h);
}

__device__ inline void edge_sd(const int* __restrict__ ei, int e, int& s, int& d) {
    if (e < E_REAL) { s = ei[e]; d = ei[E_REAL + e]; }
    else            { s = e - E_REAL; d = s; }   // self-loop
}

// async global->LDS, 16 B per lane; LDS dest = uniform base + lane*16
#define GLDS(g, l) __builtin_amdgcn_global_load_lds( \
    (const __attribute__((address_space(1))) void*)(g), \
    (__attribute__((address_space(3))) void*)(l), 16, 0, 0)

// ---------------- workspace layout (bytes) ----------------
static const long B_H1B  = 0L;           // h1b bf16 (head-major): 40,960,000
static const long B_HB   = 40960000L;    // hb  bf16 (row-major):  40,960,000
static const long B_XB   = 81920000L;    // xb / h2b bf16: 15,360,000
static const long B_W1T  = 97280000L;    // W1^T bf16
static const long B_W2T  = 100425728L;   // W2^T bf16
static const long B_SM   = 103571456L;
// small-buffer offsets (floats/ints, relative to sm)
static const long SM_AS1   = 0;         // 40000  (atomic-accumulated)
static const long SM_AD1   = 40000;     // 40000
static const long SM_AS2   = 80000;     // 10000
static const long SM_AD2   = 90000;     // 10000
static const long SM_CNT   = 100000;    // 10000 ints (zeroed each call)
static const long SM_ROWS  = 110000;    // 10001 ints
static const long SM_CURS  = 120016;    // 10000 ints
static const long SM_END   = 130016;
static const long B_CSRS = B_SM + SM_END * 4;   // 90000 ints (src)

// ---------------- fused prep: cast x, transpose W1/W2, degree histogram --
// block ranges: [0,3750) cast | [3750,5286) W1^T | [5286,6822) W2^T |
// [6822,7174) hist.
#define PREP_CAST   3750
#define PREP_T1     (PREP_CAST + 1536)     // (2048/32)*(768/32)
#define PREP_T2     (PREP_T1 + 1536)       // (768/32)*(2048/32)
#define PREP_BLOCKS (PREP_T2 + 352)        // ceil(90000/256)

__device__ inline void do_transpose(const float* __restrict__ W,
                                    ushort_t* __restrict__ WT,
                                    int K, int N, int bx, int by) {
    __shared__ ushort_t t[32][33];
    const int n0 = bx * 32, k0 = by * 32;
    const int tx = threadIdx.x & 31, ty = threadIdx.x >> 5;
#pragma unroll
    for (int i = 0; i < 4; ++i) {
        int k = ty + i * 8;
        t[k][tx] = f2b(W[(long)(k0 + k) * N + n0 + tx]);
    }
    __syncthreads();
#pragma unroll
    for (int i = 0; i < 4; ++i) {
        int n = ty + i * 8;
        WT[(long)(n0 + n) * K + k0 + tx] = t[tx][n];
    }
}

__global__ __launch_bounds__(256)
void prep(const float* __restrict__ x, ushort_t* __restrict__ xb,
          const float* __restrict__ W1, ushort_t* __restrict__ w1t,
          const float* __restrict__ W2, ushort_t* __restrict__ w2t,
          const int* __restrict__ ei, int* __restrict__ cnt) {
    const int bid = blockIdx.x;
    if (bid < PREP_CAST) {
        long i = ((long)bid * 256 + threadIdx.x) * 8;
        float4 v0 = *(const float4*)(x + i);
        float4 v1 = *(const float4*)(x + i + 4);
        ushort_t r[8] = {f2b(v0.x), f2b(v0.y), f2b(v0.z), f2b(v0.w),
                         f2b(v1.x), f2b(v1.y), f2b(v1.z), f2b(v1.w)};
        *(uint4*)(xb + i) = *(uint4*)r;
    } else if (bid < PREP_T1) {
        int b = bid - PREP_CAST;                 // W1: [768][2048] -> [2048][768]
        do_transpose(W1, w1t, IN_DIM, HD1, b & 63, b >> 6);
    } else if (bid < PREP_T2) {
        int b = bid - PREP_T1;                   // W2: [2048][768] -> [768][2048]
        do_transpose(W2, w2t, HD1, OUT_DIM, b % 24, b / 24);
    } else {
        int e = (bid - PREP_T2) * 256 + threadIdx.x;
        if (e < E_TOTAL) {
            int s, d; edge_sd(ei, e, s, d);
            atomicAdd(&cnt[d], 1);
        }
    }
}

// ---------------- bf16 MFMA GEMM + fused attention dots ------------------
// C = A[M,K] @ BT[N,K]^T.  CMODE 0: C row-major bf16; CMODE 1: head-split.
// 1-D grid with XCD supergroup swizzle: supergroup = 8 stripes x CB cols;
// within it stripe = bid%8 (constant per XCD under linear round-robin),
// col walks -> each XCD keeps one A-stripe + full B in its private L2.
// Epilogue also accumulates as/ad partial dots (fp32 acc x a_vec) via
// 16-lane shuffle reduce + atomicAdd (replaces the attn kernels).
typedef short bf16x8 __attribute__((ext_vector_type(8)));
typedef float f32x4 __attribute__((ext_vector_type(4)));

#define BM 128
#define BN 128
#define BK 32

template<int CMODE>
__global__ __launch_bounds__(256)
void gemm_bf16(const ushort_t* __restrict__ A, const ushort_t* __restrict__ BT,
               ushort_t* __restrict__ C, int M, int N, int K,
               const float* __restrict__ a_s, const float* __restrict__ a_d,
               float* __restrict__ os, float* __restrict__ od) {
    __shared__ ushort_t As[BM * BK];
    __shared__ ushort_t Bs[BN * BK];
    const int CB = N / BN;
    const int bid = blockIdx.x;
    const int sg = bid / (8 * CB), wi = bid % (8 * CB);
    const int stripe = sg * 8 + (wi & 7);
    const int bm = stripe * BM, bn = (wi >> 3) * BN;
    if (bm >= M) return;

    const int tid  = threadIdx.x;
    const int wave = tid >> 6, lane = tid & 63;
    const int quad = lane >> 4, l16 = lane & 15;
    const int wr = (wave >> 1) * 64, wc = (wave & 1) * 64;

    const int ch0 = wave * 128 + lane;
    const int ch1 = ch0 + 64;
    const int r0 = ch0 >> 2, c0 = (ch0 & 3) ^ ((r0 >> 1) & 3);
    const int r1 = ch1 >> 2, c1 = (ch1 & 3) ^ ((r1 >> 1) & 3);
    const ushort_t* a0 = A + (long)(bm + r0) * K + c0 * 8;
    const ushort_t* a1 = A + (long)(bm + r1) * K + c1 * 8;
    const ushort_t* b0 = BT + (long)(bn + r0) * K + c0 * 8;
    const ushort_t* b1 = BT + (long)(bn + r1) * K + c1 * 8;
    ushort_t* lA0 = As + (wave * 128) * 8;        // HW adds lane*16 B
    ushort_t* lA1 = As + (wave * 128 + 64) * 8;
    ushort_t* lB0 = Bs + (wave * 128) * 8;
    ushort_t* lB1 = Bs + (wave * 128 + 64) * 8;

    const int swz = (l16 >> 1) & 3;
    f32x4 acc[4][4] = {};

    for (int k0 = 0; k0 < K; k0 += BK) {
        GLDS(a0 + k0, lA0);
        GLDS(a1 + k0, lA1);
        GLDS(b0 + k0, lB0);
        GLDS(b1 + k0, lB1);
        __syncthreads();
        bf16x8 af[4], bfr[4];
#pragma unroll
        for (int i = 0; i < 4; ++i) {
            af[i]  = *(const bf16x8*)(As + ((wr + i * 16 + l16) * 4 + (quad ^ swz)) * 8);
            bfr[i] = *(const bf16x8*)(Bs + ((wc + i * 16 + l16) * 4 + (quad ^ swz)) * 8);
        }
#pragma unroll
        for (int i = 0; i < 4; ++i)
#pragma unroll
            for (int j = 0; j < 4; ++j)
                acc[i][j] = __builtin_amdgcn_mfma_f32_16x16x32_bf16(
                    af[i], bfr[j], acc[i][j], 0, 0, 0);
        __syncthreads();
    }

    // ---- C store ----
#pragma unroll
    for (int i = 0; i < 4; ++i) {
#pragma unroll
        for (int r = 0; r < 4; ++r) {
            int row = bm + wr + i * 16 + quad * 4 + r;
            if (row >= M) continue;
#pragma unroll
            for (int j = 0; j < 4; ++j) {
                int col = bn + wc + j * 16 + l16;
                if (CMODE == 0) {
                    C[(long)row * N + col] = f2b(acc[i][j][r]);
                } else {
                    C[(long)(col >> 9) * H1_HSTRIDE + (long)row * HID + (col & 511)]
                        = f2b(acc[i][j][r]);
                }
            }
        }
    }

    // ---- fused attention partial dots (this wave's 64-col span) ----
    const int cbase = bn + wc;                 // 64-aligned -> single head
    const int hidx = (CMODE == 1) ? (cbase >> 9) : 0;
    const float* aS = (CMODE == 1) ? a_s + hidx * HID : a_s;
    const float* aD = (CMODE == 1) ? a_d + hidx * HID : a_d;
    float asv[4], adv[4];
#pragma unroll
    for (int j = 0; j < 4; ++j) {
        int col = cbase + j * 16 + l16;
        int ch = (CMODE == 1) ? (col & 511) : col;
        asv[j] = aS[ch]; adv[j] = aD[ch];
    }
#pragma unroll
    for (int i = 0; i < 4; ++i) {
#pragma unroll
        for (int r = 0; r < 4; ++r) {
            float ss = 0.f, sd = 0.f;
#pragma unroll
            for (int j = 0; j < 4; ++j) {
                float v = acc[i][j][r];
                ss += v * asv[j]; sd += v * adv[j];
            }
#pragma unroll
            for (int m = 8; m >= 1; m >>= 1) {
                ss += __shfl_xor(ss, m);
                sd += __shfl_xor(sd, m);
            }
            if (l16 == 0) {
                int row = bm + wr + i * 16 + quad * 4 + r;
                if (row < M) {
                    if (CMODE == 1) {
                        atomicAdd(&os[row * HEADS + hidx], ss);
                        atomicAdd(&od[row * HEADS + hidx], sd);
                    } else {
                        atomicAdd(&os[row], ss);
                        atomicAdd(&od[row], sd);
                    }
                }
            }
        }
    }
}

// ---------------- CSR scan + scatter ----------------
#define SCAN_CH 40
__global__ __launch_bounds__(256)
void scan_nodes(const int* __restrict__ cnt, int* __restrict__ rows,
                int* __restrict__ curs) {
    __shared__ int part[256];
    const int tid = threadIdx.x;
    const int base = tid * SCAN_CH;
    int local[SCAN_CH];
    int sum = 0;
#pragma unroll
    for (int i = 0; i < SCAN_CH; ++i) {
        int idx = base + i;
        int v = (idx < N_NODES) ? cnt[idx] : 0;
        local[i] = v; sum += v;
    }
    part[tid] = sum;
    __syncthreads();
    for (int off = 1; off < 256; off <<= 1) {
        int v = (tid >= off) ? part[tid - off] : 0;
        __syncthreads();
        part[tid] += v;
        __syncthreads();
    }
    int run = part[tid] - sum;   // exclusive prefix
#pragma unroll
    for (int i = 0; i < SCAN_CH; ++i) {
        int idx = base + i;
        if (idx < N_NODES) { rows[idx] = run; curs[idx] = run; run += local[i]; }
    }
    if (tid == 255) rows[N_NODES] = run;
}

__global__ __launch_bounds__(256)
void scatter_edges(const int* __restrict__ ei, int* __restrict__ curs,
                   int* __restrict__ csr_src) {
    int e = blockIdx.x * 256 + threadIdx.x;
    if (e >= E_TOTAL) return;
    int s, d; edge_sd(ei, e, s, d);
    int pos = atomicAdd(&curs[d], 1);
    csr_src[pos] = s;
}

// ---------------- layer-1 aggregate + fused softmax + bias + ELU ---------
__global__ __launch_bounds__(64)
void agg1(const int* __restrict__ rows, const int* __restrict__ csr_src,
          const float* __restrict__ as_n, const float* __restrict__ ad_n,
          const ushort_t* __restrict__ hf, const float* __restrict__ b1,
          ushort_t* __restrict__ o) {
    const int n = blockIdx.x, hh = blockIdx.y, lane = threadIdx.x;
    const int beg = rows[n], end = rows[n + 1];
    const ushort_t* hsl = hf + (long)hh * H1_HSTRIDE;
    const float adv = ad_n[(long)n * HEADS + hh];
    float acc[8] = {};
    float dsum = 0.f;
    for (int k = beg; k < end; k += 4) {
        int nk = end - k; if (nk > 4) nk = 4;
        uint4 v[4]; float ex[4];
#pragma unroll
        for (int u = 0; u < 4; ++u) {
            if (u < nk) {
                int s = csr_src[k + u];
                float sc = as_n[(long)s * HEADS + hh] + adv;
                sc = sc > 0.f ? sc : NEG_SLOPE * sc;
                ex[u] = __expf(sc);
                v[u]  = *(const uint4*)(hsl + (long)s * HID + lane * 8);
            }
        }
#pragma unroll
        for (int u = 0; u < 4; ++u) {
            if (u < nk) {
                dsum += ex[u];
                const ushort_t* p = (const ushort_t*)&v[u];
#pragma unroll
                for (int c = 0; c < 8; ++c) acc[c] += ex[u] * b2f(p[c]);
            }
        }
    }
    const float dinv = 1.f / (dsum + 1e-16f);
    const float* bp = b1 + hh * HID + lane * 8;
    ushort_t r[8];
#pragma unroll
    for (int c = 0; c < 8; ++c) {
        float vv = acc[c] * dinv + bp[c];
        r[c] = f2b(vv > 0.f ? vv : expm1f(vv));
    }
    *(uint4*)(o + (long)n * HD1 + hh * HID + lane * 8) = *(uint4*)r;
}

// ---------------- layer-2 aggregate + fused softmax + bias -> fp32 -------
__global__ __launch_bounds__(64)
void agg2(const int* __restrict__ rows, const int* __restrict__ csr_src,
          const float* __restrict__ as_n, const float* __restrict__ ad_n,
          const ushort_t* __restrict__ hf, const float* __restrict__ b2,
          float* __restrict__ out) {
    const int n = blockIdx.x, lane = threadIdx.x;
    const int beg = rows[n], end = rows[n + 1];
    const float adv = ad_n[n];
    float acc[12] = {};
    float dsum = 0.f;
    for (int k = beg; k < end; k += 4) {
        int nk = end - k; if (nk > 4) nk = 4;
        uint4 v4[4]; uint2 v2[4]; float ex[4];
#pragma unroll
        for (int u = 0; u < 4; ++u) {
            if (u < nk) {
                int s = csr_src[k + u];
                float sc = as_n[s] + adv;
                sc = sc > 0.f ? sc : NEG_SLOPE * sc;
                ex[u] = __expf(sc);
                const ushort_t* hp = hf + (long)s * OUT_DIM;
                v4[u] = *(const uint4*)(hp + lane * 8);
                v2[u] = *(const uint2*)(hp + 512 + lane * 4);
            }
        }
#pragma unroll
        for (int u = 0; u < 4; ++u) {
            if (u < nk) {
                dsum += ex[u];
                const ushort_t* p4 = (const ushort_t*)&v4[u];
                const ushort_t* p2 = (const ushort_t*)&v2[u];
#pragma unroll
                for (int c = 0; c < 8; ++c) acc[c] += ex[u] * b2f(p4[c]);
#pragma unroll
                for (int c = 0; c < 4; ++c) acc[8 + c] += ex[u] * b2f(p2[c]);
            }
        }
    }
    const float dinv = 1.f / (dsum + 1e-16f);
    float* op = out + (long)n * OUT_DIM;
#pragma unroll
    for (int c = 0; c < 8; ++c)
        op[lane * 8 + c] = acc[c] * dinv + b2[lane * 8 + c];
#pragma unroll
    for (int c = 0; c < 4; ++c)
        op[512 + lane * 4 + c] = acc[8 + c] * dinv + b2[512 + lane * 4 + c];
}

extern "C" void kernel_launch(void* const* d_in, const int* in_sizes, int n_in,
                              void* d_out, int out_size, void* d_ws, size_t ws_size,
                              hipStream_t stream) {
    const float* x   = (const float*)d_in[0];
    const int*   ei  = (const int*)d_in[1];
    const float* W1  = (const float*)d_in[2];
    const float* a1s = (const float*)d_in[3];
    const float* a1d = (const float*)d_in[4];
    const float* b1  = (const float*)d_in[5];
    const float* W2  = (const float*)d_in[6];
    const float* a2s = (const float*)d_in[7];
    const float* a2d = (const float*)d_in[8];
    const float* b2  = (const float*)d_in[9];
    float* out = (float*)d_out;
    char* base = (char*)d_ws;

    ushort_t* h1b = (ushort_t*)(base + B_H1B);   // head-major [4][10000][512]
    ushort_t* hb  = (ushort_t*)(base + B_HB);    // row-major  [10000][2048]
    ushort_t* xb  = (ushort_t*)(base + B_XB);
    ushort_t* h2b = xb;
    ushort_t* w1t = (ushort_t*)(base + B_W1T);
    ushort_t* w2t = (ushort_t*)(base + B_W2T);
    float*    sm  = (float*)(base + B_SM);

    float* as1  = sm + SM_AS1;
    float* ad1  = sm + SM_AD1;
    float* as2  = sm + SM_AS2;
    float* ad2  = sm + SM_AD2;
    int* cnt    = (int*)(sm + SM_CNT);
    int* rows   = (int*)(sm + SM_ROWS);
    int* curs   = (int*)(sm + SM_CURS);
    int* csr_src = (int*)(base + B_CSRS);

    // zero as1/ad1/as2/ad2 (atomic-accumulated) + cnt: floats [0, 110000)
    hipMemsetAsync(sm, 0, 110000 * sizeof(float), stream);

    // ---------------- fused prep + CSR build ----------------
    prep<<<PREP_BLOCKS, 256, 0, stream>>>(x, xb, W1, w1t, W2, w2t, ei, cnt);
    scan_nodes<<<1, 256, 0, stream>>>(cnt, rows, curs);
    scatter_edges<<<(E_TOTAL + 255) / 256, 256, 0, stream>>>(ei, curs, csr_src);

    // ---------------- layer 1: GATConv(768 -> 512, heads=4, concat) --------
    // grid: supergroups of 8 stripes x 16 col-blocks; ceil(79/8)=10 SGs
    gemm_bf16<1><<<10 * 8 * (HD1 / BN), 256, 0, stream>>>(
        xb, w1t, h1b, N_NODES, HD1, IN_DIM, a1s, a1d, as1, ad1);
    agg1<<<dim3(N_NODES, HEADS), 64, 0, stream>>>(
        rows, csr_src, as1, ad1, h1b, b1, hb);

    // ---------------- layer 2: GATConv(2048 -> 768, heads=1, mean) ---------
    gemm_bf16<0><<<10 * 8 * (OUT_DIM / BN), 256, 0, stream>>>(
        hb, w2t, h2b, N_NODES, OUT_DIM, HD1, a2s, a2d, as2, ad2);
    agg2<<<N_NODES, 64, 0, stream>>>(
        rows, csr_src, as2, ad2, h2b, b2, out);
}